// Round 1
// baseline (18570.613 us; speedup 1.0000x reference)
//
#include <hip/hip_runtime.h>
#include <hip/hip_bf16.h>

typedef __hip_bfloat16 bf16;
typedef short v8s __attribute__((ext_vector_type(8)));
typedef float v4f __attribute__((ext_vector_type(4)));

// Problem constants
#define Hdim 1024
#define Bsz  64
#define Tlen 512
#define TS   511   // timesteps computed (T-1)
#define NV   256   // vocab

static __device__ __forceinline__ float bf2f(bf16 x) { return __bfloat162float(x); }

// ---------------- zero state + loss ----------------
__global__ __launch_bounds__(256) void k_zero(float* __restrict__ state, float* __restrict__ loss) {
    int idx = blockIdx.x * 256 + threadIdx.x;
    if (idx < 262144) state[idx] = 0.0f;     // h0(2),h1(2) bf16 + c0,c1 f32 = 1 MiB
    if (idx == 0) loss[0] = 0.0f;
}

// ---------------- convert recurrent weights to bf16, K-concat layout ----------------
// Wb[l][n][k2], k2<1024 -> Wih[l][n][k2], else Whh[l][n][k2-1024]
__global__ __launch_bounds__(256) void k_convert_w(const float* __restrict__ Wih,
                                                   const float* __restrict__ Whh,
                                                   bf16* __restrict__ Wb) {
    int idx = blockIdx.x * 256 + threadIdx.x;    // < 2*4096*2048 = 16,777,216
    int k2 = idx & 2047;
    int ln = idx >> 11;                           // l*4096 + n
    float v = (k2 < 1024) ? Wih[ln * 1024 + k2] : Whh[ln * 1024 + (k2 - 1024)];
    Wb[idx] = __float2bfloat16(v);
}

// ---------------- convert Wout to bf16 + bias sums ----------------
__global__ __launch_bounds__(256) void k_convert_small(const float* __restrict__ Wout,
                                                       const float* __restrict__ bih,
                                                       const float* __restrict__ bhh,
                                                       bf16* __restrict__ Wob,
                                                       float* __restrict__ bsum) {
    int idx = blockIdx.x * 256 + threadIdx.x;
    if (idx < 262144) Wob[idx] = __float2bfloat16(Wout[idx]);
    int bidx = idx - 262144;
    if (bidx >= 0 && bidx < 8192) bsum[bidx] = bih[bidx] + bhh[bidx];
}

// ---------------- embedding gather -> bf16, layout [t][b][k] ----------------
__global__ __launch_bounds__(256) void k_embed(const int* __restrict__ X,
                                               const float* __restrict__ embed,
                                               bf16* __restrict__ x0) {
    int bi = blockIdx.x;          // (t*64 + b)*4 + kc
    int kc = bi & 3;
    int tb = bi >> 2;             // t*64 + b
    int b  = tb & 63;
    int t  = tb >> 6;
    int k  = kc * 256 + threadIdx.x;
    int tok = X[b * 512 + t];     // X[:, :-1]
    x0[(long)tb * 1024 + k] = __float2bfloat16(embed[tok * 1024 + k]);
}

// ---------------- fused LSTM cell: gates GEMM (K=2048 bf16 MFMA) + activations ----------------
// grid 256: WG j owns hidden dims j*4..j*4+3 -> 16 gate columns (4 gates x 4 dims).
// block 256 = 4 waves; wave w computes M-tile batches 16w..16w+15.
__global__ __launch_bounds__(256) void k_cell(const bf16* __restrict__ xsrc,   // [64][1024]
                                              const bf16* __restrict__ hsrc,   // [64][1024]
                                              bf16* __restrict__ hdst,         // [64][1024]
                                              float* __restrict__ cbuf,        // [64][1024] f32
                                              const bf16* __restrict__ Wb,     // [4096][2048] (layer slice)
                                              const float* __restrict__ bsum,  // [4096]
                                              bf16* __restrict__ resout) {     // [64][1024]
    __shared__ float gtile[16][65];   // [q = 4*gate+col][batch], padded
    const int tid  = threadIdx.x;
    const int lane = tid & 63;
    const int w    = tid >> 6;        // 0..3
    const int j    = blockIdx.x;      // hidden-dim block
    const int q    = lane & 15;       // N index within tile: q = 4*gate + col
    const int oct  = lane >> 4;       // k-octet 0..3
    const int n    = ((q >> 2) << 10) + (j << 2) + (q & 3);   // global gate row
    const bf16* wrow = Wb + (long)n * 2048 + (oct << 3);
    const int arow = (w << 4) + q;    // A-fragment batch row
    const bf16* xa = xsrc + arow * 1024 + (oct << 3);
    const bf16* ha = hsrc + arow * 1024 + (oct << 3);
    v4f acc = {0.f, 0.f, 0.f, 0.f};
#pragma unroll
    for (int k0 = 0; k0 < 1024; k0 += 32) {      // x @ Wih^T
        v8s a  = *(const v8s*)(xa + k0);
        v8s bb = *(const v8s*)(wrow + k0);
        acc = __builtin_amdgcn_mfma_f32_16x16x32_bf16(a, bb, acc, 0, 0, 0);
    }
#pragma unroll
    for (int k0 = 0; k0 < 1024; k0 += 32) {      // h @ Whh^T
        v8s a  = *(const v8s*)(ha + k0);
        v8s bb = *(const v8s*)(wrow + 1024 + k0);
        acc = __builtin_amdgcn_mfma_f32_16x16x32_bf16(a, bb, acc, 0, 0, 0);
    }
    const float bias = bsum[n];
#pragma unroll
    for (int r = 0; r < 4; ++r)                   // D: col=lane&15, row=(lane>>4)*4+r
        gtile[q][(w << 4) + (oct << 2) + r] = acc[r] + bias;
    __syncthreads();

    // activation phase: thread -> (col c = w, batch b = lane)
    const int hd = (j << 2) + w;
    const int b  = lane;
    const float gi = gtile[w][b];          // i: q = 0*4+c
    const float gf = gtile[4 + w][b];      // f
    const float gg = gtile[8 + w][b];      // g
    const float go = gtile[12 + w][b];     // o
    const float si = 1.f / (1.f + __expf(-gi));
    const float sf = 1.f / (1.f + __expf(-gf));
    const float so = 1.f / (1.f + __expf(-go));
    const float tg = tanhf(gg);
    const int ci = b * 1024 + hd;
    const float cn = sf * cbuf[ci] + si * tg;
    cbuf[ci] = cn;
    const float hn = so * tanhf(cn);
    hdst[ci] = __float2bfloat16(hn);
    resout[ci] = __float2bfloat16(hn + bf2f(xsrc[ci]));   // residual: h + inp
}

// ---------------- output projection + CE, one WG per timestep ----------------
__global__ __launch_bounds__(256) void k_final(const bf16* __restrict__ outAll, // [511][64][1024]
                                               const bf16* __restrict__ Wob,    // [256][1024]
                                               const float* __restrict__ bout,  // [256]
                                               const int* __restrict__ X,       // [64][512]
                                               float* __restrict__ loss) {
    const int t    = blockIdx.x;
    const int tid  = threadIdx.x;
    const int lane = tid & 63;
    const int w    = tid >> 6;
    const int col  = lane & 15;
    const int oct  = lane >> 4;
    const bf16* arow = outAll + ((long)t * 64 + (w << 4) + col) * 1024 + (oct << 3);
    v4f acc[16];
#pragma unroll
    for (int nt = 0; nt < 16; ++nt) acc[nt] = (v4f){0.f, 0.f, 0.f, 0.f};
    for (int k0 = 0; k0 < 1024; k0 += 32) {
        v8s a = *(const v8s*)(arow + k0);
#pragma unroll
        for (int nt = 0; nt < 16; ++nt) {
            v8s bb = *(const v8s*)(Wob + ((nt << 4) + col) * 1024 + (oct << 3) + k0);
            acc[nt] = __builtin_amdgcn_mfma_f32_16x16x32_bf16(a, bb, acc[nt], 0, 0, 0);
        }
    }
#pragma unroll
    for (int nt = 0; nt < 16; ++nt) {
        const float bb = bout[(nt << 4) + col];
        acc[nt][0] += bb; acc[nt][1] += bb; acc[nt][2] += bb; acc[nt][3] += bb;
    }
    float ce_sum = 0.f;
#pragma unroll
    for (int r = 0; r < 4; ++r) {
        float mx = -3.4e38f;
#pragma unroll
        for (int nt = 0; nt < 16; ++nt) mx = fmaxf(mx, acc[nt][r]);
#pragma unroll
        for (int m = 1; m < 16; m <<= 1) mx = fmaxf(mx, __shfl_xor(mx, m, 64));
        float s = 0.f;
#pragma unroll
        for (int nt = 0; nt < 16; ++nt) s += __expf(acc[nt][r] - mx);
#pragma unroll
        for (int m = 1; m < 16; m <<= 1) s += __shfl_xor(s, m, 64);
        const int b   = (w << 4) + (oct << 2) + r;
        const int tok = X[b * 512 + t + 1];        // targets X[:, 1:]
        float lt = 0.f;
#pragma unroll
        for (int nt = 0; nt < 16; ++nt)            // static indexing (no scratch spill)
            if ((tok >> 4) == nt) lt = acc[nt][r];
        if ((tok & 15) == col)
            ce_sum += mx + __logf(s) - lt;
    }
#pragma unroll
    for (int m = 1; m < 64; m <<= 1) ce_sum += __shfl_xor(ce_sum, m, 64);
    if (lane == 0) atomicAdd(loss, ce_sum * (1.0f / 32768.0f));   // /(64*512)
}

extern "C" void kernel_launch(void* const* d_in, const int* in_sizes, int n_in,
                              void* d_out, int out_size, void* d_ws, size_t ws_size,
                              hipStream_t stream) {
    const int*   X     = (const int*)  d_in[0];
    const float* embed = (const float*)d_in[1];
    const float* Wih   = (const float*)d_in[2];
    const float* Whh   = (const float*)d_in[3];
    const float* bih   = (const float*)d_in[4];
    const float* bhh   = (const float*)d_in[5];
    const float* Wout  = (const float*)d_in[6];
    const float* bout  = (const float*)d_in[7];
    float* loss = (float*)d_out;

    // workspace layout (bytes); total = 102,268,928
    char* ws = (char*)d_ws;
    bf16*  x0all = (bf16*)(ws + 0);           // 511*64*1024 bf16 (x0, later overwritten by out[t])
    bf16*  Wb    = (bf16*)(ws + 66977792);    // 2*4096*2048 bf16
    bf16*  Wob   = (bf16*)(ws + 100532224);   // 256*1024 bf16
    bf16*  x1    = (bf16*)(ws + 101056512);   // 64*1024 bf16
    bf16*  h0    = (bf16*)(ws + 101187584);   // 2*64*1024 bf16 (double buffer)
    bf16*  h1    = (bf16*)(ws + 101449728);   // 2*64*1024 bf16
    float* c0    = (float*)(ws + 101711872);  // 64*1024 f32
    float* c1    = (float*)(ws + 101974016);  // 64*1024 f32
    float* bsum  = (float*)(ws + 102236160);  // 2*4096 f32
    float* state = (float*)(ws + 101187584);  // h0,h1,c0,c1 contiguous = 262144 f32

    if (ws_size < 102268928u) return;         // visible failure if ws too small

    k_zero<<<1024, 256, 0, stream>>>(state, loss);
    k_convert_w<<<65536, 256, 0, stream>>>(Wih, Whh, Wb);
    k_convert_small<<<1056, 256, 0, stream>>>(Wout, bih, bhh, Wob, bsum);
    k_embed<<<130816, 256, 0, stream>>>(X, embed, x0all);

    for (int t = 0; t < 511; ++t) {
        bf16* x0t = x0all + (long)t * 65536;
        // layer 0: reads x0[t], h0 ; writes h0', c0, x1 = h0' + x0[t]
        k_cell<<<256, 256, 0, stream>>>(x0t,
                                        h0 + (t & 1) * 65536, h0 + ((t + 1) & 1) * 65536,
                                        c0, Wb, bsum, x1);
        // layer 1: reads x1, h1 ; writes h1', c1, out[t] = h1' + x1 (overwrites x0[t])
        k_cell<<<256, 256, 0, stream>>>(x1,
                                        h1 + (t & 1) * 65536, h1 + ((t + 1) & 1) * 65536,
                                        c1, Wb + 8388608, bsum + 4096, x0t);
    }
    k_final<<<511, 256, 0, stream>>>(x0all, Wob, bout, X, loss);
}